// Round 1
// 3153.109 us; speedup vs baseline: 1.1240x; 1.1240x over previous
//
#include <hip/hip_runtime.h>

// varletNetworks on MI355X — round 3: close_edge moved to split-bf16 MFMA.
// Round-2 counters: close_edge 605us, MfmaUtil 0, VALUBusy 63%, HBM 10.6% —
// a VALU-bound fp32 GEMM with idle matrix cores. Fix: hi/lo bf16 split
// (Ahi*Bhi + Ahi*Blo + Alo*Bhi, error ~2^-16 rel) on v_mfma_f32_16x16x32_bf16.
// Weights pre-packed in fragment order (prep_close_w); xe frags loaded
// directly from global (64B-coalesced), Sacc frags are k-contiguous dwordx4.

#define HSTEP 0.1f
#define TVEPS 1e-3f

typedef __attribute__((ext_vector_type(8))) short short8v;
typedef __attribute__((ext_vector_type(4))) float f32x4;

__device__ inline float4 f4z() { return make_float4(0.f, 0.f, 0.f, 0.f); }

__device__ inline unsigned short f2bf(float x) {
  unsigned u = __float_as_uint(x);
  unsigned r = (u + 0x7fffu + ((u >> 16) & 1u)) >> 16;
  return (unsigned short)r;
}
__device__ inline float bf2f(unsigned short h) {
  return __uint_as_float(((unsigned)h) << 16);
}

// ---------------------------------------------------------------------------
// E-style GEMM: X in [128,N] layout; block = 64 cols x 128 outs; store [N,128]
// ---------------------------------------------------------------------------
__global__ __launch_bounds__(256, 2) void gemm_e(
    const float* __restrict__ X, const float* __restrict__ Kmat, const int N,
    float* __restrict__ Yt) {
  __shared__ float Xs[32 * 68];   // [kk][e] pad 68
  __shared__ float Ks[32 * 132];  // [kk][o] pad 132
  const int tid = threadIdx.x;
  const int ng = tid & 15, og = tid >> 4;
  const long e0 = (long)blockIdx.x * 64;

  float acc[4][8];
#pragma unroll
  for (int q = 0; q < 4; ++q)
#pragma unroll
    for (int j = 0; j < 8; ++j) acc[q][j] = 0.f;

  for (int kc = 0; kc < 128; kc += 32) {
#pragma unroll
    for (int i = 0; i < 2; ++i) {
      int f4i = tid + 256 * i;  // 512 float4s
      int kk = f4i >> 4, e4 = (f4i & 15) << 2;
      long ge = e0 + e4;
      float4 v = f4z();
      if (ge + 3 < N) {
        v = *(const float4*)&X[(long)(kc + kk) * N + ge];
      } else {
        float* pv = &v.x;
        for (int q = 0; q < 4; ++q)
          if (ge + q < N) pv[q] = X[(long)(kc + kk) * N + ge + q];
      }
      *(float4*)&Xs[kk * 68 + e4] = v;
    }
#pragma unroll
    for (int i = 0; i < 4; ++i) {
      int f4i = tid + 256 * i;  // 1024 float4s
      int o = f4i >> 3, c4 = (f4i & 7) << 2;
      float4 v = *(const float4*)&Kmat[o * 128 + kc + c4];
      Ks[(c4 + 0) * 132 + o] = v.x;
      Ks[(c4 + 1) * 132 + o] = v.y;
      Ks[(c4 + 2) * 132 + o] = v.z;
      Ks[(c4 + 3) * 132 + o] = v.w;
    }
    __syncthreads();
#pragma unroll
    for (int kk = 0; kk < 32; ++kk) {
      const float4 xq = *(const float4*)&Xs[kk * 68 + 4 * ng];
      const float4 k0 = *(const float4*)&Ks[kk * 132 + 8 * og];
      const float4 k1 = *(const float4*)&Ks[kk * 132 + 8 * og + 4];
      float xv[4] = {xq.x, xq.y, xq.z, xq.w};
      float kv[8] = {k0.x, k0.y, k0.z, k0.w, k1.x, k1.y, k1.z, k1.w};
#pragma unroll
      for (int q = 0; q < 4; ++q)
#pragma unroll
        for (int j = 0; j < 8; ++j) acc[q][j] = fmaf(xv[q], kv[j], acc[q][j]);
    }
    __syncthreads();
  }

#pragma unroll
  for (int q = 0; q < 4; ++q) {
    long e = e0 + 4 * ng + q;
    if (e < N) {
      *(float4*)&Yt[e * 128 + 8 * og] =
          make_float4(acc[q][0], acc[q][1], acc[q][2], acc[q][3]);
      *(float4*)&Yt[e * 128 + 8 * og + 4] =
          make_float4(acc[q][4], acc[q][5], acc[q][6], acc[q][7]);
    }
  }
}

// ---------------------------------------------------------------------------
// N-style GEMM: X in [N,128]; out[n][o] = sum_k X[n][k]*Kmat[o][k]
// MODE 0: store [N,128]. MODE 1: relu+store+stats. MODE 2: store [128,N].
// ---------------------------------------------------------------------------
template <int MODE>
__global__ __launch_bounds__(256, 2) void gemm_n(
    const float* __restrict__ X, const float* __restrict__ Kmat, const int N,
    float* __restrict__ Y, float* __restrict__ statS,
    float* __restrict__ statQ) {
  __shared__ float Xs[64 * 33];
  __shared__ float Ks[32 * 132];
  __shared__ float red[(MODE == 1) ? 2 * 128 * 17 : 4];
  const int tid = threadIdx.x;
  const int ng = tid & 15, og = tid >> 4;
  const long n0 = (long)blockIdx.x * 64;

  float acc[4][8];
#pragma unroll
  for (int q = 0; q < 4; ++q)
#pragma unroll
    for (int j = 0; j < 8; ++j) acc[q][j] = 0.f;

  for (int kc = 0; kc < 128; kc += 32) {
#pragma unroll
    for (int i = 0; i < 2; ++i) {
      int f4i = tid + 256 * i;
      int n = f4i >> 3, c4 = (f4i & 7) << 2;
      long gn = n0 + n;
      float4 v = f4z();
      if (gn < N) v = *(const float4*)&X[gn * 128 + kc + c4];
      Xs[n * 33 + c4 + 0] = v.x;
      Xs[n * 33 + c4 + 1] = v.y;
      Xs[n * 33 + c4 + 2] = v.z;
      Xs[n * 33 + c4 + 3] = v.w;
    }
#pragma unroll
    for (int i = 0; i < 4; ++i) {
      int f4i = tid + 256 * i;
      int o = f4i >> 3, c4 = (f4i & 7) << 2;
      float4 v = *(const float4*)&Kmat[o * 128 + kc + c4];
      Ks[(c4 + 0) * 132 + o] = v.x;
      Ks[(c4 + 1) * 132 + o] = v.y;
      Ks[(c4 + 2) * 132 + o] = v.z;
      Ks[(c4 + 3) * 132 + o] = v.w;
    }
    __syncthreads();
#pragma unroll
    for (int kk = 0; kk < 32; ++kk) {
      float xv[4];
#pragma unroll
      for (int q = 0; q < 4; ++q) xv[q] = Xs[(4 * ng + q) * 33 + kk];
      const float4 k0 = *(const float4*)&Ks[kk * 132 + 8 * og];
      const float4 k1 = *(const float4*)&Ks[kk * 132 + 8 * og + 4];
      float kv[8] = {k0.x, k0.y, k0.z, k0.w, k1.x, k1.y, k1.z, k1.w};
#pragma unroll
      for (int q = 0; q < 4; ++q)
#pragma unroll
        for (int j = 0; j < 8; ++j) acc[q][j] = fmaf(xv[q], kv[j], acc[q][j]);
    }
    __syncthreads();
  }

  if (MODE == 0) {
#pragma unroll
    for (int q = 0; q < 4; ++q) {
      long n = n0 + 4 * ng + q;
      if (n < N) {
        *(float4*)&Y[n * 128 + 8 * og] =
            make_float4(acc[q][0], acc[q][1], acc[q][2], acc[q][3]);
        *(float4*)&Y[n * 128 + 8 * og + 4] =
            make_float4(acc[q][4], acc[q][5], acc[q][6], acc[q][7]);
      }
    }
  } else if (MODE == 1) {
#pragma unroll
    for (int q = 0; q < 4; ++q)
#pragma unroll
      for (int j = 0; j < 8; ++j) acc[q][j] = fmaxf(acc[q][j], 0.f);
#pragma unroll
    for (int q = 0; q < 4; ++q) {
      long n = n0 + 4 * ng + q;
      if (n < N) {
        *(float4*)&Y[n * 128 + 8 * og] =
            make_float4(acc[q][0], acc[q][1], acc[q][2], acc[q][3]);
        *(float4*)&Y[n * 128 + 8 * og + 4] =
            make_float4(acc[q][4], acc[q][5], acc[q][6], acc[q][7]);
      }
    }
    float* redS = red;
    float* redQ = red + 128 * 17;
#pragma unroll
    for (int j = 0; j < 8; ++j) {
      int o = 8 * og + j;
      float s = acc[0][j] + acc[1][j] + acc[2][j] + acc[3][j];
      float qq = acc[0][j] * acc[0][j] + acc[1][j] * acc[1][j] +
                 acc[2][j] * acc[2][j] + acc[3][j] * acc[3][j];
      redS[o * 17 + ng] = s;
      redQ[o * 17 + ng] = qq;
    }
    __syncthreads();
    if (tid < 128) {
      float s = 0.f, qq = 0.f;
#pragma unroll
      for (int g = 0; g < 16; ++g) {
        s += redS[tid * 17 + g];
        qq += redQ[tid * 17 + g];
      }
      atomicAdd(&statS[tid], s);
      atomicAdd(&statQ[tid], qq);
    }
  } else {  // MODE 2: transposed store
    long n = n0 + 4 * ng;
#pragma unroll
    for (int j = 0; j < 8; ++j) {
      long o = 8 * og + j;
      float4 v = make_float4(acc[0][j], acc[1][j], acc[2][j], acc[3][j]);
      if (n + 3 < N) {
        *(float4*)&Y[o * N + n] = v;
      } else {
        const float* pv = &v.x;
        for (int q = 0; q < 4; ++q)
          if (n + q < N) Y[o * N + n + q] = pv[q];
      }
    }
  }
}

// ---------------------------------------------------------------------------
// prep_close_w: pack M1 = KNclose@KEopen and Kc = KNclose as hi/lo bf16 in
// MFMA fragment order. Layout (ushorts):
//   chunk(p,ks) = p*4 + (k>>5), each 8192 ushorts (16KB):
//     h*4096 + (o>>4)*512 + lane*8 + (k&7),  lane = (o&15) + 16*((k>>3)&3)
// ---------------------------------------------------------------------------
__global__ __launch_bounds__(256) void prep_close_w(
    const float* __restrict__ KNclose, const float* __restrict__ KEopen,
    unsigned short* __restrict__ Apack) {
  const int idx = blockIdx.x * 256 + threadIdx.x;  // 32768
  const int p = idx >> 14, ok = idx & 16383;
  const int o = ok >> 7, k = ok & 127;
  float val;
  if (p == 0) {
    float s = 0.f;
    for (int m = 0; m < 128; ++m)
      s = fmaf(KNclose[o * 128 + m], KEopen[m * 128 + k], s);
    val = s;
  } else {
    val = KNclose[o * 128 + k];
  }
  const unsigned short hi = f2bf(val);
  const unsigned short lo = f2bf(val - bf2f(hi));
  const int chunk = p * 4 + (k >> 5);
  const int lane = (o & 15) + 16 * ((k >> 3) & 3);
  const int base = chunk * 8192 + (o >> 4) * 512 + lane * 8 + (k & 7);
  Apack[base] = hi;
  Apack[base + 4096] = lo;
}

// ---------------------------------------------------------------------------
// close_edge_mfma: out[o][e] = sum_k M1[o][k]*xe[k][e] + Kc[o][k]*Sacc[e][k]
// Split-bf16: acc += Ahi*Bhi + Ahi*Blo + Alo*Bhi (drops ~2^-16 rel term).
// Block: 256 thr = 4 waves; E tile 128 (32 e per wave = 2 frags); O = 128.
// A staged per kstep as linear 16KB LDS copy; frag reads conflict-free.
// ---------------------------------------------------------------------------
__global__ __launch_bounds__(256, 2) void close_edge_mfma(
    const float* __restrict__ xe, const float* __restrict__ Sacc,
    const unsigned short* __restrict__ Apack, const int nE,
    float* __restrict__ out) {
  __shared__ float4 Asf[1024];  // 16KB: hi slab [0,512) short8v, lo [512,1024)
  const int tid = threadIdx.x;
  const int l = tid & 63, w = tid >> 6;
  const int er = l & 15;   // e within frag / o within A-row
  const int kg = l >> 4;   // k-group (8 k's each)
  const long e0 = (long)blockIdx.x * 128;

  f32x4 acc[8][2];
#pragma unroll
  for (int of = 0; of < 8; ++of)
#pragma unroll
    for (int f = 0; f < 2; ++f) acc[of][f] = (f32x4){0.f, 0.f, 0.f, 0.f};

  long e_f[2];
  bool ev[2];
#pragma unroll
  for (int f = 0; f < 2; ++f) {
    long e = e0 + 32 * w + 16 * f + er;
    ev[f] = (e < nE);
    e_f[f] = ev[f] ? e : (long)(nE - 1);
  }

  const short8v* Ap = (const short8v*)Asf;

  for (int p = 0; p < 2; ++p) {
    for (int ks = 0; ks < 4; ++ks) {
      // ---- stage A chunk (16KB linear) ----
      const float4* src = (const float4*)Apack + (p * 4 + ks) * 1024;
      __syncthreads();  // previous iter's reads done before overwrite
      Asf[tid] = src[tid];
      Asf[tid + 256] = src[tid + 256];
      Asf[tid + 512] = src[tid + 512];
      Asf[tid + 768] = src[tid + 768];
      __syncthreads();

      // ---- B fragments (hi/lo) ----
      short8v bh[2], bl[2];
#pragma unroll
      for (int f = 0; f < 2; ++f) {
        float xv[8];
        if (p == 0) {
          const float* col = xe + e_f[f];
          const int kbase = 32 * ks + 8 * kg;
#pragma unroll
          for (int j = 0; j < 8; ++j) xv[j] = col[(long)(kbase + j) * nE];
        } else {
          const float* row = Sacc + e_f[f] * 128 + 32 * ks + 8 * kg;
          const float4 v0 = *(const float4*)row;
          const float4 v1 = *(const float4*)(row + 4);
          xv[0] = v0.x; xv[1] = v0.y; xv[2] = v0.z; xv[3] = v0.w;
          xv[4] = v1.x; xv[5] = v1.y; xv[6] = v1.z; xv[7] = v1.w;
        }
#pragma unroll
        for (int j = 0; j < 8; ++j) {
          const unsigned short h = f2bf(xv[j]);
          const unsigned short lo = f2bf(xv[j] - bf2f(h));
          bh[f][j] = (short)h;
          bl[f][j] = (short)lo;
        }
      }

      // ---- MFMA ----
#pragma unroll
      for (int of = 0; of < 8; ++of) {
        const short8v ah = Ap[of * 64 + l];
        const short8v al = Ap[512 + of * 64 + l];
#pragma unroll
        for (int f = 0; f < 2; ++f) {
          acc[of][f] =
              __builtin_amdgcn_mfma_f32_16x16x32_bf16(ah, bh[f], acc[of][f], 0, 0, 0);
          acc[of][f] =
              __builtin_amdgcn_mfma_f32_16x16x32_bf16(ah, bl[f], acc[of][f], 0, 0, 0);
          acc[of][f] =
              __builtin_amdgcn_mfma_f32_16x16x32_bf16(al, bh[f], acc[of][f], 0, 0, 0);
        }
      }
    }
  }

  // ---- store: D row = 4*kg + r (within frag), col = er ----
#pragma unroll
  for (int of = 0; of < 8; ++of) {
#pragma unroll
    for (int f = 0; f < 2; ++f) {
      if (!ev[f]) continue;
      const long e = e0 + 32 * w + 16 * f + er;
#pragma unroll
      for (int r = 0; r < 4; ++r) {
        const long o = of * 16 + 4 * kg + r;
        out[o * nE + e] = acc[of][f][r];
      }
    }
  }
}

// ---------------------------------------------------------------------------
// CSR build: counts -> scan -> fill. Entry = (e<<1)|sign (sign 1 => minus).
// ---------------------------------------------------------------------------
__global__ __launch_bounds__(256) void count_deg(const int* __restrict__ iInd,
                                                 const int* __restrict__ jInd,
                                                 const int nE,
                                                 int* __restrict__ cnt) {
  const int e = blockIdx.x * 256 + threadIdx.x;
  if (e >= nE) return;
  atomicAdd(&cnt[iInd[e]], 1);
  atomicAdd(&cnt[jInd[e]], 1);
}

__global__ __launch_bounds__(1024) void scan_rowptr(const int* __restrict__ cnt,
                                                    int* __restrict__ rp,
                                                    const int nN) {
  __shared__ int buf[1024];
  __shared__ int carry;
  const int tid = threadIdx.x;
  if (tid == 0) {
    carry = 0;
    rp[0] = 0;
  }
  __syncthreads();
  for (int base = 0; base < nN; base += 1024) {
    int idx = base + tid;
    int v = (idx < nN) ? cnt[idx] : 0;
    buf[tid] = v;
    __syncthreads();
    for (int off = 1; off < 1024; off <<= 1) {
      int t = (tid >= off) ? buf[tid - off] : 0;
      __syncthreads();
      buf[tid] += t;
      __syncthreads();
    }
    if (idx < nN) rp[idx + 1] = buf[tid] + carry;
    __syncthreads();
    if (tid == 0) carry += buf[1023];
    __syncthreads();
  }
}

__global__ __launch_bounds__(256) void fill_adj(const int* __restrict__ iInd,
                                                const int* __restrict__ jInd,
                                                const int nE,
                                                const int* __restrict__ rp,
                                                int* __restrict__ cur,
                                                int* __restrict__ adj) {
  const int e = blockIdx.x * 256 + threadIdx.x;
  if (e >= nE) return;
  const int ii = iInd[e], jj = jInd[e];
  int s1 = atomicAdd(&cur[ii], 1);
  adj[rp[ii] + s1] = (e << 1);
  int s2 = atomicAdd(&cur[jj], 1);
  adj[rp[jj] + s2] = (e << 1) | 1;
}

// ---------------------------------------------------------------------------
// div_gather: D[n,:] = (OPEN ? 0 : D0[n,:]) + sum_{(e,s) in adj(n)} +-E[e,:]
// ---------------------------------------------------------------------------
template <bool OPEN>
__global__ __launch_bounds__(256) void div_gather(
    const float* __restrict__ E, const int* __restrict__ rp,
    const int* __restrict__ adj, const float* __restrict__ D0,
    float* __restrict__ D, const int nN) {
  const int cg = threadIdx.x & 31, slot = threadIdx.x >> 5;
  const long n = (long)blockIdx.x * 8 + slot;
  if (n >= nN) return;
  const float4* E4 = (const float4*)E;
  float4 acc;
  if (OPEN) {
    acc = f4z();
  } else {
    acc = ((const float4*)D0)[n * 32 + cg];
  }
  const int b = rp[n], en = rp[n + 1];
  for (int k = b; k < en; ++k) {
    const int ent = adj[k];
    const long e = ent >> 1;
    const float4 v = E4[e * 32 + cg];
    if (ent & 1) {
      acc.x -= v.x; acc.y -= v.y; acc.z -= v.z; acc.w -= v.w;
    } else {
      acc.x += v.x; acc.y += v.y; acc.z += v.z; acc.w += v.w;
    }
  }
  ((float4*)D)[n * 32 + cg] = acc;
}

// ---------------------------------------------------------------------------
// Edge pass 1: per-channel sum/sumsq of y = W[i]-W[j].
// ---------------------------------------------------------------------------
__global__ __launch_bounds__(256) void edge_pass1(
    const float* __restrict__ W, const int* __restrict__ iInd,
    const int* __restrict__ jInd, const int nE, float* __restrict__ statS,
    float* __restrict__ statQ) {
  __shared__ float4 rs[256];
  __shared__ float4 rq[256];
  const int tid = threadIdx.x;
  const int cg = tid & 31, slot = tid >> 5;
  const float4* W4 = (const float4*)W;
  float4 s = f4z(), q = f4z();
  long start = (long)blockIdx.x * 512;
  long end = start + 512;
  if (end > nE) end = nE;
  for (long e = start + slot; e < end; e += 8) {
    const int ii = iInd[e], jj = jInd[e];
    const float4 wi = W4[(long)ii * 32 + cg];
    const float4 wj = W4[(long)jj * 32 + cg];
    const float y0 = wi.x - wj.x, y1 = wi.y - wj.y;
    const float y2 = wi.z - wj.z, y3 = wi.w - wj.w;
    s.x += y0; s.y += y1; s.z += y2; s.w += y3;
    q.x = fmaf(y0, y0, q.x); q.y = fmaf(y1, y1, q.y);
    q.z = fmaf(y2, y2, q.z); q.w = fmaf(y3, y3, q.w);
  }
  rs[tid] = s;
  rq[tid] = q;
  __syncthreads();
  if (tid < 32) {
    float4 S = rs[tid], Q = rq[tid];
#pragma unroll
    for (int g = 1; g < 8; ++g) {
      float4 a = rs[tid + 32 * g], b = rq[tid + 32 * g];
      S.x += a.x; S.y += a.y; S.z += a.z; S.w += a.w;
      Q.x += b.x; Q.y += b.y; Q.z += b.z; Q.w += b.w;
    }
    atomicAdd(&statS[tid * 4 + 0], S.x);
    atomicAdd(&statS[tid * 4 + 1], S.y);
    atomicAdd(&statS[tid * 4 + 2], S.z);
    atomicAdd(&statS[tid * 4 + 3], S.w);
    atomicAdd(&statQ[tid * 4 + 0], Q.x);
    atomicAdd(&statQ[tid * 4 + 1], Q.y);
    atomicAdd(&statQ[tid * 4 + 2], Q.z);
    atomicAdd(&statQ[tid * 4 + 3], Q.w);
  }
}

// ---------------------------------------------------------------------------
// Edge pass 2: r = H*relu((y-mean)*rsig); Sacc (=) or (+=) r. No atomics.
// ---------------------------------------------------------------------------
template <bool FIRST>
__global__ __launch_bounds__(256) void edge_pass2(
    const float* __restrict__ W, const int* __restrict__ iInd,
    const int* __restrict__ jInd, const int nE, const float* __restrict__ mean,
    const float* __restrict__ rsig, float* __restrict__ Sacc) {
  const int tid = threadIdx.x;
  const int cg = tid & 31, slot = tid >> 5;
  const float4 mu = *(const float4*)&mean[cg * 4];
  const float4 sg = *(const float4*)&rsig[cg * 4];
  const float4* W4 = (const float4*)W;
  float4* S4 = (float4*)Sacc;
  long start = (long)blockIdx.x * 512;
  long end = start + 512;
  if (end > nE) end = nE;
  for (long e = start + slot; e < end; e += 8) {
    const int ii = iInd[e], jj = jInd[e];
    const float4 wi = W4[(long)ii * 32 + cg];
    const float4 wj = W4[(long)jj * 32 + cg];
    const float r0 = fmaxf(((wi.x - wj.x) - mu.x) * sg.x, 0.f) * HSTEP;
    const float r1 = fmaxf(((wi.y - wj.y) - mu.y) * sg.y, 0.f) * HSTEP;
    const float r2 = fmaxf(((wi.z - wj.z) - mu.z) * sg.z, 0.f) * HSTEP;
    const float r3 = fmaxf(((wi.w - wj.w) - mu.w) * sg.w, 0.f) * HSTEP;
    float4 sv;
    if (FIRST) {
      sv = make_float4(r0, r1, r2, r3);
    } else {
      sv = S4[e * 32 + cg];
      sv.x += r0; sv.y += r1; sv.z += r2; sv.w += r3;
    }
    S4[e * 32 + cg] = sv;
  }
}

// ---------------------------------------------------------------------------
__global__ void fin_stats(const float* __restrict__ S,
                          const float* __restrict__ Q, const float cnt,
                          float* __restrict__ mean, float* __restrict__ rsig) {
  const int c = threadIdx.x;  // 128
  const float mu = S[c] / cnt;
  const float var = Q[c] - cnt * mu * mu;
  mean[c] = mu;
  rsig[c] = rsqrtf(var + TVEPS);
}

__global__ __launch_bounds__(256) void apply_node(
    const float* __restrict__ R, const float* __restrict__ mean,
    const float* __restrict__ rsig, float* __restrict__ xnt,
    const long total4) {
  const long idx = (long)blockIdx.x * 256 + threadIdx.x;
  if (idx >= total4) return;
  const int o4 = (int)(idx & 31) * 4;
  const float4 m = *(const float4*)&mean[o4];
  const float4 s = *(const float4*)&rsig[o4];
  const float4 r = ((const float4*)R)[idx];
  float4 x = ((float4*)xnt)[idx];
  x.x += HSTEP * fmaxf((r.x - m.x) * s.x, 0.f);
  x.y += HSTEP * fmaxf((r.y - m.y) * s.y, 0.f);
  x.z += HSTEP * fmaxf((r.z - m.z) * s.z, 0.f);
  x.w += HSTEP * fmaxf((r.w - m.w) * s.w, 0.f);
  ((float4*)xnt)[idx] = x;
}

// ---------------------------------------------------------------------------
extern "C" void kernel_launch(void* const* d_in, const int* in_sizes, int n_in,
                              void* d_out, int out_size, void* d_ws,
                              size_t ws_size, hipStream_t stream) {
  const float* xn = (const float*)d_in[0];
  const float* xe = (const float*)d_in[1];
  const int* iInd = (const int*)d_in[2];
  const int* jInd = (const int*)d_in[3];
  const float* KNopen = (const float*)d_in[4];
  const float* KEopen = (const float*)d_in[5];
  const float* KNclose = (const float*)d_in[6];
  const float* KN = (const float*)d_in[8];
  const float* KE = (const float*)d_in[9];

  const int nN = in_sizes[0] / 128;
  const int nE = in_sizes[2];

  float* out_xn = (float*)d_out;
  float* out_xe = (float*)d_out + (size_t)128 * nN;

  float* ws = (float*)d_ws;
  size_t off = 0;
  float* Sacc = ws + off; off += (size_t)nE * 128;  // 256 MB; aliases Eopen
  float* W    = ws + off; off += (size_t)nN * 128;  // also reused as R
  float* Dacc = ws + off; off += (size_t)nN * 128;
  float* D0   = ws + off; off += (size_t)nN * 128;
  float* xnt  = ws + off; off += (size_t)nN * 128;
  unsigned short* Apack = (unsigned short*)(ws + off); off += 32768;  // 128KB
  float* stats = ws + off; off += 1024;
  float* statS = stats;        float* statQ = stats + 128;
  float* meanE = stats + 256;  float* rsigE = stats + 384;
  float* statS2 = stats + 512; float* statQ2 = stats + 640;
  float* meanN = stats + 768;  float* rsigN = stats + 896;
  int* rp  = (int*)(ws + off); off += (size_t)nN + 1 + 63;  // row_ptr
  int* cnt = (int*)(ws + off); off += nN;
  int* cur = (int*)(ws + off); off += nN;
  int* adj = (int*)(ws + off); off += (size_t)2 * nE;
  float* Eopen = Sacc;  // alias: Eopen dead after div_gather<true>
  float* R = W;         // alias: W dead after edge_pass2

  const int gN = (nN + 63) / 64;
  const int gE = (nE + 63) / 64;
  const int gEm = (nE + 127) / 128;
  const int gP = (nE + 511) / 512;
  const int gEdge = (nE + 255) / 256;
  const int gGath = (nN + 7) / 8;
  const int gA = (int)(((long)nN * 32 + 255) / 256);

  // ---- CSR build ----
  hipMemsetAsync(cnt, 0, (size_t)nN * sizeof(int), stream);
  hipMemsetAsync(cur, 0, (size_t)nN * sizeof(int), stream);
  count_deg<<<gEdge, 256, 0, stream>>>(iInd, jInd, nE, cnt);
  scan_rowptr<<<1, 1024, 0, stream>>>(cnt, rp, nN);
  fill_adj<<<gEdge, 256, 0, stream>>>(iInd, jInd, nE, rp, cur, adj);

  // ---- open ----
  gemm_e<<<gN, 256, 0, stream>>>(xn, KNopen, nN, xnt);          // xnt [nN,128]
  gemm_e<<<gE, 256, 0, stream>>>(xe, KEopen, nE, Eopen);        // [nE,128]
  prep_close_w<<<128, 256, 0, stream>>>(KNclose, KEopen, Apack);
  div_gather<true><<<gGath, 256, 0, stream>>>(Eopen, rp, adj, nullptr, D0, nN);

  // ---- layers ----
  for (int layer = 0; layer < 4; ++layer) {
    hipMemsetAsync(stats, 0, 1024 * sizeof(float), stream);
    gemm_n<0><<<gN, 256, 0, stream>>>(xnt, KN + layer * 16384, nN, W, nullptr,
                                      nullptr);
    edge_pass1<<<gP, 256, 0, stream>>>(W, iInd, jInd, nE, statS, statQ);
    fin_stats<<<1, 128, 0, stream>>>(statS, statQ, (float)nE, meanE, rsigE);
    if (layer == 0)
      edge_pass2<true><<<gP, 256, 0, stream>>>(W, iInd, jInd, nE, meanE, rsigE,
                                               Sacc);
    else
      edge_pass2<false><<<gP, 256, 0, stream>>>(W, iInd, jInd, nE, meanE,
                                                rsigE, Sacc);
    div_gather<false><<<gGath, 256, 0, stream>>>(Sacc, rp, adj, D0, Dacc, nN);
    gemm_n<1><<<gN, 256, 0, stream>>>(Dacc, KE + layer * 16384, nN, R, statS2,
                                      statQ2);
    fin_stats<<<1, 128, 0, stream>>>(statS2, statQ2, (float)nN, meanN, rsigN);
    apply_node<<<gA, 256, 0, stream>>>(R, meanN, rsigN, xnt, (long)nN * 32);
  }

  // ---- close ----
  gemm_n<2><<<gN, 256, 0, stream>>>(xnt, KNclose, nN, out_xn, nullptr,
                                    nullptr);
  close_edge_mfma<<<gEm, 256, 0, stream>>>(xe, Sacc, Apack, nE, out_xe);
}

// Round 2
// 2978.518 us; speedup vs baseline: 1.1899x; 1.0586x over previous
//
#include <hip/hip_runtime.h>

// varletNetworks on MI355X — round 4: all no-stats GEMMs moved to split-bf16
// MFMA (recipe validated by close_edge_mfma in round 3: predicted and got
// ~390us). Round-3 counters: gemm_e(xe) 217us, MfmaUtil 0, VALUBusy 64% —
// VALU-bound fp32 GEMM, memory floor is ~90us. Converted: gemm_e (xn & xe
// open), gemm_n<0> (KN@xnt per layer), gemm_n<2> (node close; reuses the
// KNclose pack inside Apack). gemm_n<1> (stats epilogue) stays fp32 for now.
// Weights packed once per launch by pack6/prep_close_w in MFMA frag order.

#define HSTEP 0.1f
#define TVEPS 1e-3f

typedef __attribute__((ext_vector_type(8))) short short8v;
typedef __attribute__((ext_vector_type(4))) float f32x4;

__device__ inline float4 f4z() { return make_float4(0.f, 0.f, 0.f, 0.f); }

__device__ inline unsigned short f2bf(float x) {
  unsigned u = __float_as_uint(x);
  unsigned r = (u + 0x7fffu + ((u >> 16) & 1u)) >> 16;
  return (unsigned short)r;
}
__device__ inline float bf2f(unsigned short h) {
  return __uint_as_float(((unsigned)h) << 16);
}

// ---------------------------------------------------------------------------
// Packing layout (per 128x128 matrix, ushorts):
//   chunk ks = k>>5 (4 chunks of 8192: hi [0,4096), lo [4096,8192))
//   within: (o>>4)*512 + lane*8 + (k&7), lane = (o&15) + 16*((k>>3)&3)
// Consumer: Ap[of*64 + l] (hi), Ap[512 + of*64 + l] (lo) per staged chunk.
// ---------------------------------------------------------------------------
__global__ __launch_bounds__(256) void pack6(const float* __restrict__ KNopen,
                                             const float* __restrict__ KEopen,
                                             const float* __restrict__ KN,
                                             unsigned short* __restrict__ dst) {
  const int idx = blockIdx.x * 256 + threadIdx.x;  // 16384 per matrix
  const int m = blockIdx.y;                        // 6 matrices
  const int o = idx >> 7, k = idx & 127;
  const float* src;
  if (m == 0) src = KNopen;
  else if (m == 1) src = KEopen;
  else src = KN + (m - 2) * 16384;
  const float val = src[o * 128 + k];
  const unsigned short hi = f2bf(val);
  const unsigned short lo = f2bf(val - bf2f(hi));
  const int lane = (o & 15) + 16 * ((k >> 3) & 3);
  const int base =
      m * 32768 + (k >> 5) * 8192 + (o >> 4) * 512 + lane * 8 + (k & 7);
  dst[base] = hi;
  dst[base + 4096] = lo;
}

// prep_close_w: pack M1 = KNclose@KEopen (p=0) and Kc = KNclose (p=1).
__global__ __launch_bounds__(256) void prep_close_w(
    const float* __restrict__ KNclose, const float* __restrict__ KEopen,
    unsigned short* __restrict__ Apack) {
  const int idx = blockIdx.x * 256 + threadIdx.x;  // 32768
  const int p = idx >> 14, ok = idx & 16383;
  const int o = ok >> 7, k = ok & 127;
  float val;
  if (p == 0) {
    float s = 0.f;
    for (int m = 0; m < 128; ++m)
      s = fmaf(KNclose[o * 128 + m], KEopen[m * 128 + k], s);
    val = s;
  } else {
    val = KNclose[o * 128 + k];
  }
  const unsigned short hi = f2bf(val);
  const unsigned short lo = f2bf(val - bf2f(hi));
  const int chunk = p * 4 + (k >> 5);
  const int lane = (o & 15) + 16 * ((k >> 3) & 3);
  const int base = chunk * 8192 + (o >> 4) * 512 + lane * 8 + (k & 7);
  Apack[base] = hi;
  Apack[base + 4096] = lo;
}

// ---------------------------------------------------------------------------
// gemm_e_mfma: X [128,N] channel-major; Y[e][o] = sum_k K[o][k]X[k][e],
// stored [N,128]. Block = 4 waves, 128-e tile, full 128 o.
// ---------------------------------------------------------------------------
__global__ __launch_bounds__(256, 2) void gemm_e_mfma(
    const float* __restrict__ X, const unsigned short* __restrict__ Wp,
    const int N, float* __restrict__ Yt) {
  __shared__ float4 Asf[1024];  // 16KB chunk: hi [0,512) short8v, lo [512,1024)
  const int tid = threadIdx.x;
  const int l = tid & 63, w = tid >> 6;
  const int er = l & 15, kg = l >> 4;
  const long e0 = (long)blockIdx.x * 128;

  f32x4 acc[8][2];
#pragma unroll
  for (int of = 0; of < 8; ++of)
#pragma unroll
    for (int f = 0; f < 2; ++f) acc[of][f] = (f32x4){0.f, 0.f, 0.f, 0.f};

  long e_f[2];
  bool ev[2];
#pragma unroll
  for (int f = 0; f < 2; ++f) {
    long e = e0 + 32 * w + 16 * f + er;
    ev[f] = (e < N);
    e_f[f] = ev[f] ? e : (long)(N - 1);
  }

  const short8v* Ap = (const short8v*)Asf;

  for (int ks = 0; ks < 4; ++ks) {
    const float4* src = (const float4*)Wp + ks * 1024;
    __syncthreads();
    Asf[tid] = src[tid];
    Asf[tid + 256] = src[tid + 256];
    Asf[tid + 512] = src[tid + 512];
    Asf[tid + 768] = src[tid + 768];
    __syncthreads();

    short8v bh[2], bl[2];
#pragma unroll
    for (int f = 0; f < 2; ++f) {
      const float* col = X + e_f[f];
      const int kbase = 32 * ks + 8 * kg;
      float xv[8];
#pragma unroll
      for (int j = 0; j < 8; ++j) xv[j] = col[(long)(kbase + j) * N];
#pragma unroll
      for (int j = 0; j < 8; ++j) {
        const unsigned short h = f2bf(xv[j]);
        const unsigned short lo = f2bf(xv[j] - bf2f(h));
        bh[f][j] = (short)h;
        bl[f][j] = (short)lo;
      }
    }

#pragma unroll
    for (int of = 0; of < 8; ++of) {
      const short8v ah = Ap[of * 64 + l];
      const short8v al = Ap[512 + of * 64 + l];
#pragma unroll
      for (int f = 0; f < 2; ++f) {
        acc[of][f] =
            __builtin_amdgcn_mfma_f32_16x16x32_bf16(ah, bh[f], acc[of][f], 0, 0, 0);
        acc[of][f] =
            __builtin_amdgcn_mfma_f32_16x16x32_bf16(ah, bl[f], acc[of][f], 0, 0, 0);
        acc[of][f] =
            __builtin_amdgcn_mfma_f32_16x16x32_bf16(al, bh[f], acc[of][f], 0, 0, 0);
      }
    }
  }

  // store: row o = of*16 + 4*kg + r, col e = er -> float4 per (of,f)
#pragma unroll
  for (int of = 0; of < 8; ++of) {
#pragma unroll
    for (int f = 0; f < 2; ++f) {
      if (!ev[f]) continue;
      *(f32x4*)&Yt[e_f[f] * 128 + of * 16 + 4 * kg] = acc[of][f];
    }
  }
}

// ---------------------------------------------------------------------------
// gemm_n_mfma: X [N,128] row-major; Y[n][o] = sum_k X[n][k]K[o][k].
// MODE 0: store [N,128]. MODE 2: store [128,N].
// ---------------------------------------------------------------------------
template <int MODE>
__global__ __launch_bounds__(256, 2) void gemm_n_mfma(
    const float* __restrict__ X, const unsigned short* __restrict__ Wp,
    const int N, float* __restrict__ Y) {
  __shared__ float4 Asf[1024];
  const int tid = threadIdx.x;
  const int l = tid & 63, w = tid >> 6;
  const int er = l & 15, kg = l >> 4;
  const long n0 = (long)blockIdx.x * 128;

  f32x4 acc[8][2];
#pragma unroll
  for (int of = 0; of < 8; ++of)
#pragma unroll
    for (int f = 0; f < 2; ++f) acc[of][f] = (f32x4){0.f, 0.f, 0.f, 0.f};

  long n_f[2];
  bool nv[2];
#pragma unroll
  for (int f = 0; f < 2; ++f) {
    long n = n0 + 32 * w + 16 * f + er;
    nv[f] = (n < N);
    n_f[f] = nv[f] ? n : (long)(N - 1);
  }

  const short8v* Ap = (const short8v*)Asf;

  for (int ks = 0; ks < 4; ++ks) {
    const float4* src = (const float4*)Wp + ks * 1024;
    __syncthreads();
    Asf[tid] = src[tid];
    Asf[tid + 256] = src[tid + 256];
    Asf[tid + 512] = src[tid + 512];
    Asf[tid + 768] = src[tid + 768];
    __syncthreads();

    short8v bh[2], bl[2];
#pragma unroll
    for (int f = 0; f < 2; ++f) {
      const float* row = X + n_f[f] * 128 + 32 * ks + 8 * kg;
      const float4 v0 = *(const float4*)row;
      const float4 v1 = *(const float4*)(row + 4);
      float xv[8] = {v0.x, v0.y, v0.z, v0.w, v1.x, v1.y, v1.z, v1.w};
#pragma unroll
      for (int j = 0; j < 8; ++j) {
        const unsigned short h = f2bf(xv[j]);
        const unsigned short lo = f2bf(xv[j] - bf2f(h));
        bh[f][j] = (short)h;
        bl[f][j] = (short)lo;
      }
    }

#pragma unroll
    for (int of = 0; of < 8; ++of) {
      const short8v ah = Ap[of * 64 + l];
      const short8v al = Ap[512 + of * 64 + l];
#pragma unroll
      for (int f = 0; f < 2; ++f) {
        acc[of][f] =
            __builtin_amdgcn_mfma_f32_16x16x32_bf16(ah, bh[f], acc[of][f], 0, 0, 0);
        acc[of][f] =
            __builtin_amdgcn_mfma_f32_16x16x32_bf16(ah, bl[f], acc[of][f], 0, 0, 0);
        acc[of][f] =
            __builtin_amdgcn_mfma_f32_16x16x32_bf16(al, bh[f], acc[of][f], 0, 0, 0);
      }
    }
  }

  if (MODE == 0) {
#pragma unroll
    for (int of = 0; of < 8; ++of) {
#pragma unroll
      for (int f = 0; f < 2; ++f) {
        if (!nv[f]) continue;
        *(f32x4*)&Y[n_f[f] * 128 + of * 16 + 4 * kg] = acc[of][f];
      }
    }
  } else {  // MODE 2: transposed store [128,N]
#pragma unroll
    for (int of = 0; of < 8; ++of) {
#pragma unroll
      for (int f = 0; f < 2; ++f) {
        if (!nv[f]) continue;
#pragma unroll
        for (int r = 0; r < 4; ++r) {
          const long o = of * 16 + 4 * kg + r;
          Y[o * N + n_f[f]] = acc[of][f][r];
        }
      }
    }
  }
}

// ---------------------------------------------------------------------------
// gemm_n<1> (fp32): X [N,128]; relu + store [N,128] + per-channel stats.
// ---------------------------------------------------------------------------
__global__ __launch_bounds__(256, 2) void gemm_n1(
    const float* __restrict__ X, const float* __restrict__ Kmat, const int N,
    float* __restrict__ Y, float* __restrict__ statS,
    float* __restrict__ statQ) {
  __shared__ float Xs[64 * 33];
  __shared__ float Ks[32 * 132];
  __shared__ float red[2 * 128 * 17];
  const int tid = threadIdx.x;
  const int ng = tid & 15, og = tid >> 4;
  const long n0 = (long)blockIdx.x * 64;

  float acc[4][8];
#pragma unroll
  for (int q = 0; q < 4; ++q)
#pragma unroll
    for (int j = 0; j < 8; ++j) acc[q][j] = 0.f;

  for (int kc = 0; kc < 128; kc += 32) {
#pragma unroll
    for (int i = 0; i < 2; ++i) {
      int f4i = tid + 256 * i;
      int n = f4i >> 3, c4 = (f4i & 7) << 2;
      long gn = n0 + n;
      float4 v = f4z();
      if (gn < N) v = *(const float4*)&X[gn * 128 + kc + c4];
      Xs[n * 33 + c4 + 0] = v.x;
      Xs[n * 33 + c4 + 1] = v.y;
      Xs[n * 33 + c4 + 2] = v.z;
      Xs[n * 33 + c4 + 3] = v.w;
    }
#pragma unroll
    for (int i = 0; i < 4; ++i) {
      int f4i = tid + 256 * i;
      int o = f4i >> 3, c4 = (f4i & 7) << 2;
      float4 v = *(const float4*)&Kmat[o * 128 + kc + c4];
      Ks[(c4 + 0) * 132 + o] = v.x;
      Ks[(c4 + 1) * 132 + o] = v.y;
      Ks[(c4 + 2) * 132 + o] = v.z;
      Ks[(c4 + 3) * 132 + o] = v.w;
    }
    __syncthreads();
#pragma unroll
    for (int kk = 0; kk < 32; ++kk) {
      float xv[4];
#pragma unroll
      for (int q = 0; q < 4; ++q) xv[q] = Xs[(4 * ng + q) * 33 + kk];
      const float4 k0 = *(const float4*)&Ks[kk * 132 + 8 * og];
      const float4 k1 = *(const float4*)&Ks[kk * 132 + 8 * og + 4];
      float kv[8] = {k0.x, k0.y, k0.z, k0.w, k1.x, k1.y, k1.z, k1.w};
#pragma unroll
      for (int q = 0; q < 4; ++q)
#pragma unroll
        for (int j = 0; j < 8; ++j) acc[q][j] = fmaf(xv[q], kv[j], acc[q][j]);
    }
    __syncthreads();
  }

#pragma unroll
  for (int q = 0; q < 4; ++q)
#pragma unroll
    for (int j = 0; j < 8; ++j) acc[q][j] = fmaxf(acc[q][j], 0.f);
#pragma unroll
  for (int q = 0; q < 4; ++q) {
    long n = n0 + 4 * ng + q;
    if (n < N) {
      *(float4*)&Y[n * 128 + 8 * og] =
          make_float4(acc[q][0], acc[q][1], acc[q][2], acc[q][3]);
      *(float4*)&Y[n * 128 + 8 * og + 4] =
          make_float4(acc[q][4], acc[q][5], acc[q][6], acc[q][7]);
    }
  }
  float* redS = red;
  float* redQ = red + 128 * 17;
#pragma unroll
  for (int j = 0; j < 8; ++j) {
    int o = 8 * og + j;
    float s = acc[0][j] + acc[1][j] + acc[2][j] + acc[3][j];
    float qq = acc[0][j] * acc[0][j] + acc[1][j] * acc[1][j] +
               acc[2][j] * acc[2][j] + acc[3][j] * acc[3][j];
    redS[o * 17 + ng] = s;
    redQ[o * 17 + ng] = qq;
  }
  __syncthreads();
  if (tid < 128) {
    float s = 0.f, qq = 0.f;
#pragma unroll
    for (int g = 0; g < 16; ++g) {
      s += redS[tid * 17 + g];
      qq += redQ[tid * 17 + g];
    }
    atomicAdd(&statS[tid], s);
    atomicAdd(&statQ[tid], qq);
  }
}

// ---------------------------------------------------------------------------
// close_edge_mfma: out[o][e] = sum_k M1[o][k]*xe[k][e] + Kc[o][k]*Sacc[e][k]
// ---------------------------------------------------------------------------
__global__ __launch_bounds__(256, 2) void close_edge_mfma(
    const float* __restrict__ xe, const float* __restrict__ Sacc,
    const unsigned short* __restrict__ Apack, const int nE,
    float* __restrict__ out) {
  __shared__ float4 Asf[1024];
  const int tid = threadIdx.x;
  const int l = tid & 63, w = tid >> 6;
  const int er = l & 15;
  const int kg = l >> 4;
  const long e0 = (long)blockIdx.x * 128;

  f32x4 acc[8][2];
#pragma unroll
  for (int of = 0; of < 8; ++of)
#pragma unroll
    for (int f = 0; f < 2; ++f) acc[of][f] = (f32x4){0.f, 0.f, 0.f, 0.f};

  long e_f[2];
  bool ev[2];
#pragma unroll
  for (int f = 0; f < 2; ++f) {
    long e = e0 + 32 * w + 16 * f + er;
    ev[f] = (e < nE);
    e_f[f] = ev[f] ? e : (long)(nE - 1);
  }

  const short8v* Ap = (const short8v*)Asf;

  for (int p = 0; p < 2; ++p) {
    for (int ks = 0; ks < 4; ++ks) {
      const float4* src = (const float4*)Apack + (p * 4 + ks) * 1024;
      __syncthreads();
      Asf[tid] = src[tid];
      Asf[tid + 256] = src[tid + 256];
      Asf[tid + 512] = src[tid + 512];
      Asf[tid + 768] = src[tid + 768];
      __syncthreads();

      short8v bh[2], bl[2];
#pragma unroll
      for (int f = 0; f < 2; ++f) {
        float xv[8];
        if (p == 0) {
          const float* col = xe + e_f[f];
          const int kbase = 32 * ks + 8 * kg;
#pragma unroll
          for (int j = 0; j < 8; ++j) xv[j] = col[(long)(kbase + j) * nE];
        } else {
          const float* row = Sacc + e_f[f] * 128 + 32 * ks + 8 * kg;
          const float4 v0 = *(const float4*)row;
          const float4 v1 = *(const float4*)(row + 4);
          xv[0] = v0.x; xv[1] = v0.y; xv[2] = v0.z; xv[3] = v0.w;
          xv[4] = v1.x; xv[5] = v1.y; xv[6] = v1.z; xv[7] = v1.w;
        }
#pragma unroll
        for (int j = 0; j < 8; ++j) {
          const unsigned short h = f2bf(xv[j]);
          const unsigned short lo = f2bf(xv[j] - bf2f(h));
          bh[f][j] = (short)h;
          bl[f][j] = (short)lo;
        }
      }

#pragma unroll
      for (int of = 0; of < 8; ++of) {
        const short8v ah = Ap[of * 64 + l];
        const short8v al = Ap[512 + of * 64 + l];
#pragma unroll
        for (int f = 0; f < 2; ++f) {
          acc[of][f] =
              __builtin_amdgcn_mfma_f32_16x16x32_bf16(ah, bh[f], acc[of][f], 0, 0, 0);
          acc[of][f] =
              __builtin_amdgcn_mfma_f32_16x16x32_bf16(ah, bl[f], acc[of][f], 0, 0, 0);
          acc[of][f] =
              __builtin_amdgcn_mfma_f32_16x16x32_bf16(al, bh[f], acc[of][f], 0, 0, 0);
        }
      }
    }
  }

#pragma unroll
  for (int of = 0; of < 8; ++of) {
#pragma unroll
    for (int f = 0; f < 2; ++f) {
      if (!ev[f]) continue;
      const long e = e_f[f];
#pragma unroll
      for (int r = 0; r < 4; ++r) {
        const long o = of * 16 + 4 * kg + r;
        out[o * nE + e] = acc[of][f][r];
      }
    }
  }
}

// ---------------------------------------------------------------------------
// CSR build: counts -> scan -> fill. Entry = (e<<1)|sign (sign 1 => minus).
// ---------------------------------------------------------------------------
__global__ __launch_bounds__(256) void count_deg(const int* __restrict__ iInd,
                                                 const int* __restrict__ jInd,
                                                 const int nE,
                                                 int* __restrict__ cnt) {
  const int e = blockIdx.x * 256 + threadIdx.x;
  if (e >= nE) return;
  atomicAdd(&cnt[iInd[e]], 1);
  atomicAdd(&cnt[jInd[e]], 1);
}

__global__ __launch_bounds__(1024) void scan_rowptr(const int* __restrict__ cnt,
                                                    int* __restrict__ rp,
                                                    const int nN) {
  __shared__ int buf[1024];
  __shared__ int carry;
  const int tid = threadIdx.x;
  if (tid == 0) {
    carry = 0;
    rp[0] = 0;
  }
  __syncthreads();
  for (int base = 0; base < nN; base += 1024) {
    int idx = base + tid;
    int v = (idx < nN) ? cnt[idx] : 0;
    buf[tid] = v;
    __syncthreads();
    for (int off = 1; off < 1024; off <<= 1) {
      int t = (tid >= off) ? buf[tid - off] : 0;
      __syncthreads();
      buf[tid] += t;
      __syncthreads();
    }
    if (idx < nN) rp[idx + 1] = buf[tid] + carry;
    __syncthreads();
    if (tid == 0) carry += buf[1023];
    __syncthreads();
  }
}

__global__ __launch_bounds__(256) void fill_adj(const int* __restrict__ iInd,
                                                const int* __restrict__ jInd,
                                                const int nE,
                                                const int* __restrict__ rp,
                                                int* __restrict__ cur,
                                                int* __restrict__ adj) {
  const int e = blockIdx.x * 256 + threadIdx.x;
  if (e >= nE) return;
  const int ii = iInd[e], jj = jInd[e];
  int s1 = atomicAdd(&cur[ii], 1);
  adj[rp[ii] + s1] = (e << 1);
  int s2 = atomicAdd(&cur[jj], 1);
  adj[rp[jj] + s2] = (e << 1) | 1;
}

// ---------------------------------------------------------------------------
// div_gather: D[n,:] = (OPEN ? 0 : D0[n,:]) + sum_{(e,s) in adj(n)} +-E[e,:]
// ---------------------------------------------------------------------------
template <bool OPEN>
__global__ __launch_bounds__(256) void div_gather(
    const float* __restrict__ E, const int* __restrict__ rp,
    const int* __restrict__ adj, const float* __restrict__ D0,
    float* __restrict__ D, const int nN) {
  const int cg = threadIdx.x & 31, slot = threadIdx.x >> 5;
  const long n = (long)blockIdx.x * 8 + slot;
  if (n >= nN) return;
  const float4* E4 = (const float4*)E;
  float4 acc;
  if (OPEN) {
    acc = f4z();
  } else {
    acc = ((const float4*)D0)[n * 32 + cg];
  }
  const int b = rp[n], en = rp[n + 1];
  for (int k = b; k < en; ++k) {
    const int ent = adj[k];
    const long e = ent >> 1;
    const float4 v = E4[e * 32 + cg];
    if (ent & 1) {
      acc.x -= v.x; acc.y -= v.y; acc.z -= v.z; acc.w -= v.w;
    } else {
      acc.x += v.x; acc.y += v.y; acc.z += v.z; acc.w += v.w;
    }
  }
  ((float4*)D)[n * 32 + cg] = acc;
}

// ---------------------------------------------------------------------------
// Edge pass 1: per-channel sum/sumsq of y = W[i]-W[j].
// ---------------------------------------------------------------------------
__global__ __launch_bounds__(256) void edge_pass1(
    const float* __restrict__ W, const int* __restrict__ iInd,
    const int* __restrict__ jInd, const int nE, float* __restrict__ statS,
    float* __restrict__ statQ) {
  __shared__ float4 rs[256];
  __shared__ float4 rq[256];
  const int tid = threadIdx.x;
  const int cg = tid & 31, slot = tid >> 5;
  const float4* W4 = (const float4*)W;
  float4 s = f4z(), q = f4z();
  long start = (long)blockIdx.x * 512;
  long end = start + 512;
  if (end > nE) end = nE;
  for (long e = start + slot; e < end; e += 8) {
    const int ii = iInd[e], jj = jInd[e];
    const float4 wi = W4[(long)ii * 32 + cg];
    const float4 wj = W4[(long)jj * 32 + cg];
    const float y0 = wi.x - wj.x, y1 = wi.y - wj.y;
    const float y2 = wi.z - wj.z, y3 = wi.w - wj.w;
    s.x += y0; s.y += y1; s.z += y2; s.w += y3;
    q.x = fmaf(y0, y0, q.x); q.y = fmaf(y1, y1, q.y);
    q.z = fmaf(y2, y2, q.z); q.w = fmaf(y3, y3, q.w);
  }
  rs[tid] = s;
  rq[tid] = q;
  __syncthreads();
  if (tid < 32) {
    float4 S = rs[tid], Q = rq[tid];
#pragma unroll
    for (int g = 1; g < 8; ++g) {
      float4 a = rs[tid + 32 * g], b = rq[tid + 32 * g];
      S.x += a.x; S.y += a.y; S.z += a.z; S.w += a.w;
      Q.x += b.x; Q.y += b.y; Q.z += b.z; Q.w += b.w;
    }
    atomicAdd(&statS[tid * 4 + 0], S.x);
    atomicAdd(&statS[tid * 4 + 1], S.y);
    atomicAdd(&statS[tid * 4 + 2], S.z);
    atomicAdd(&statS[tid * 4 + 3], S.w);
    atomicAdd(&statQ[tid * 4 + 0], Q.x);
    atomicAdd(&statQ[tid * 4 + 1], Q.y);
    atomicAdd(&statQ[tid * 4 + 2], Q.z);
    atomicAdd(&statQ[tid * 4 + 3], Q.w);
  }
}

// ---------------------------------------------------------------------------
// Edge pass 2: r = H*relu((y-mean)*rsig); Sacc (=) or (+=) r. No atomics.
// ---------------------------------------------------------------------------
template <bool FIRST>
__global__ __launch_bounds__(256) void edge_pass2(
    const float* __restrict__ W, const int* __restrict__ iInd,
    const int* __restrict__ jInd, const int nE, const float* __restrict__ mean,
    const float* __restrict__ rsig, float* __restrict__ Sacc) {
  const int tid = threadIdx.x;
  const int cg = tid & 31, slot = tid >> 5;
  const float4 mu = *(const float4*)&mean[cg * 4];
  const float4 sg = *(const float4*)&rsig[cg * 4];
  const float4* W4 = (const float4*)W;
  float4* S4 = (float4*)Sacc;
  long start = (long)blockIdx.x * 512;
  long end = start + 512;
  if (end > nE) end = nE;
  for (long e = start + slot; e < end; e += 8) {
    const int ii = iInd[e], jj = jInd[e];
    const float4 wi = W4[(long)ii * 32 + cg];
    const float4 wj = W4[(long)jj * 32 + cg];
    const float r0 = fmaxf(((wi.x - wj.x) - mu.x) * sg.x, 0.f) * HSTEP;
    const float r1 = fmaxf(((wi.y - wj.y) - mu.y) * sg.y, 0.f) * HSTEP;
    const float r2 = fmaxf(((wi.z - wj.z) - mu.z) * sg.z, 0.f) * HSTEP;
    const float r3 = fmaxf(((wi.w - wj.w) - mu.w) * sg.w, 0.f) * HSTEP;
    float4 sv;
    if (FIRST) {
      sv = make_float4(r0, r1, r2, r3);
    } else {
      sv = S4[e * 32 + cg];
      sv.x += r0; sv.y += r1; sv.z += r2; sv.w += r3;
    }
    S4[e * 32 + cg] = sv;
  }
}

// ---------------------------------------------------------------------------
__global__ void fin_stats(const float* __restrict__ S,
                          const float* __restrict__ Q, const float cnt,
                          float* __restrict__ mean, float* __restrict__ rsig) {
  const int c = threadIdx.x;  // 128
  const float mu = S[c] / cnt;
  const float var = Q[c] - cnt * mu * mu;
  mean[c] = mu;
  rsig[c] = rsqrtf(var + TVEPS);
}

__global__ __launch_bounds__(256) void apply_node(
    const float* __restrict__ R, const float* __restrict__ mean,
    const float* __restrict__ rsig, float* __restrict__ xnt,
    const long total4) {
  const long idx = (long)blockIdx.x * 256 + threadIdx.x;
  if (idx >= total4) return;
  const int o4 = (int)(idx & 31) * 4;
  const float4 m = *(const float4*)&mean[o4];
  const float4 s = *(const float4*)&rsig[o4];
  const float4 r = ((const float4*)R)[idx];
  float4 x = ((float4*)xnt)[idx];
  x.x += HSTEP * fmaxf((r.x - m.x) * s.x, 0.f);
  x.y += HSTEP * fmaxf((r.y - m.y) * s.y, 0.f);
  x.z += HSTEP * fmaxf((r.z - m.z) * s.z, 0.f);
  x.w += HSTEP * fmaxf((r.w - m.w) * s.w, 0.f);
  ((float4*)xnt)[idx] = x;
}

// ---------------------------------------------------------------------------
extern "C" void kernel_launch(void* const* d_in, const int* in_sizes, int n_in,
                              void* d_out, int out_size, void* d_ws,
                              size_t ws_size, hipStream_t stream) {
  const float* xn = (const float*)d_in[0];
  const float* xe = (const float*)d_in[1];
  const int* iInd = (const int*)d_in[2];
  const int* jInd = (const int*)d_in[3];
  const float* KNopen = (const float*)d_in[4];
  const float* KEopen = (const float*)d_in[5];
  const float* KNclose = (const float*)d_in[6];
  const float* KN = (const float*)d_in[8];
  const float* KE = (const float*)d_in[9];

  const int nN = in_sizes[0] / 128;
  const int nE = in_sizes[2];

  float* out_xn = (float*)d_out;
  float* out_xe = (float*)d_out + (size_t)128 * nN;

  float* ws = (float*)d_ws;
  size_t off = 0;
  float* Sacc = ws + off; off += (size_t)nE * 128;  // 256 MB; aliases Eopen
  float* W    = ws + off; off += (size_t)nN * 128;  // also reused as R
  float* Dacc = ws + off; off += (size_t)nN * 128;
  float* D0   = ws + off; off += (size_t)nN * 128;
  float* xnt  = ws + off; off += (size_t)nN * 128;
  unsigned short* Apack = (unsigned short*)(ws + off); off += 32768;  // 128KB
  unsigned short* Wpack = (unsigned short*)(ws + off); off += 98304;  // 384KB
  float* stats = ws + off; off += 1024;
  float* statS = stats;        float* statQ = stats + 128;
  float* meanE = stats + 256;  float* rsigE = stats + 384;
  float* statS2 = stats + 512; float* statQ2 = stats + 640;
  float* meanN = stats + 768;  float* rsigN = stats + 896;
  int* rp  = (int*)(ws + off); off += (size_t)nN + 1 + 63;  // row_ptr
  int* cnt = (int*)(ws + off); off += nN;
  int* cur = (int*)(ws + off); off += nN;
  int* adj = (int*)(ws + off); off += (size_t)2 * nE;
  float* Eopen = Sacc;  // alias: Eopen dead after div_gather<true>
  float* R = W;         // alias: W dead after edge_pass2

  const int gN = (nN + 63) / 64;
  const int gNm = (nN + 127) / 128;
  const int gEm = (nE + 127) / 128;
  const int gP = (nE + 511) / 512;
  const int gEdge = (nE + 255) / 256;
  const int gGath = (nN + 7) / 8;
  const int gA = (int)(((long)nN * 32 + 255) / 256);

  // ---- CSR build ----
  hipMemsetAsync(cnt, 0, (size_t)nN * sizeof(int), stream);
  hipMemsetAsync(cur, 0, (size_t)nN * sizeof(int), stream);
  count_deg<<<gEdge, 256, 0, stream>>>(iInd, jInd, nE, cnt);
  scan_rowptr<<<1, 1024, 0, stream>>>(cnt, rp, nN);
  fill_adj<<<gEdge, 256, 0, stream>>>(iInd, jInd, nE, rp, cur, adj);

  // ---- weight packs ----
  pack6<<<dim3(64, 6), 256, 0, stream>>>(KNopen, KEopen, KN, Wpack);
  prep_close_w<<<128, 256, 0, stream>>>(KNclose, KEopen, Apack);

  // ---- open ----
  gemm_e_mfma<<<gNm, 256, 0, stream>>>(xn, Wpack, nN, xnt);       // [nN,128]
  gemm_e_mfma<<<gEm, 256, 0, stream>>>(xe, Wpack + 32768, nE, Eopen);
  div_gather<true><<<gGath, 256, 0, stream>>>(Eopen, rp, adj, nullptr, D0, nN);

  // ---- layers ----
  for (int layer = 0; layer < 4; ++layer) {
    hipMemsetAsync(stats, 0, 1024 * sizeof(float), stream);
    gemm_n_mfma<0><<<gNm, 256, 0, stream>>>(
        xnt, Wpack + (size_t)(2 + layer) * 32768, nN, W);
    edge_pass1<<<gP, 256, 0, stream>>>(W, iInd, jInd, nE, statS, statQ);
    fin_stats<<<1, 128, 0, stream>>>(statS, statQ, (float)nE, meanE, rsigE);
    if (layer == 0)
      edge_pass2<true><<<gP, 256, 0, stream>>>(W, iInd, jInd, nE, meanE, rsigE,
                                               Sacc);
    else
      edge_pass2<false><<<gP, 256, 0, stream>>>(W, iInd, jInd, nE, meanE,
                                                rsigE, Sacc);
    div_gather<false><<<gGath, 256, 0, stream>>>(Sacc, rp, adj, D0, Dacc, nN);
    gemm_n1<<<gN, 256, 0, stream>>>(Dacc, KE + layer * 16384, nN, R, statS2,
                                    statQ2);
    fin_stats<<<1, 128, 0, stream>>>(statS2, statQ2, (float)nN, meanN, rsigN);
    apply_node<<<gA, 256, 0, stream>>>(R, meanN, rsigN, xnt, (long)nN * 32);
  }

  // ---- close ----
  gemm_n_mfma<2><<<gNm, 256, 0, stream>>>(xnt, Apack + 32768, nN, out_xn);
  close_edge_mfma<<<gEm, 256, 0, stream>>>(xe, Sacc, Apack, nE, out_xe);
}

// Round 4
// 2595.654 us; speedup vs baseline: 1.3654x; 1.1475x over previous
//
#include <hip/hip_runtime.h>

// varletNetworks on MI355X — round 6: round-5 restructure, ws-safe layout.
// Round-5 failed (container died twice); prime suspect is ws overflow:
// +Wb(102MB)+R(26MB)+adjO(4MB) pushed ws from ~363MB (known good) to ~444MB.
// Fix: host Wb and R in d_out's out_xe region (256MB, dead until the last
// two dispatches). ws footprint now ~318MB < 363MB known-good.
// Algorithm (unchanged from r5): div is linear -> running Dacc; r_e
// recomputed on the fly from LLC-resident W_l; Sacc built ONCE at the end
// from the 4 retained W_l (compute_sacc), killing per-layer 1GB Sacc traffic.

#define HSTEP 0.1f
#define TVEPS 1e-3f

typedef __attribute__((ext_vector_type(8))) short short8v;
typedef __attribute__((ext_vector_type(4))) float f32x4;

__device__ inline float4 f4z() { return make_float4(0.f, 0.f, 0.f, 0.f); }

__device__ inline unsigned short f2bf(float x) {
  unsigned u = __float_as_uint(x);
  unsigned r = (u + 0x7fffu + ((u >> 16) & 1u)) >> 16;
  return (unsigned short)r;
}
__device__ inline float bf2f(unsigned short h) {
  return __uint_as_float(((unsigned)h) << 16);
}

// ---------------------------------------------------------------------------
// Packing layout (per 128x128 matrix, ushorts):
//   chunk ks = k>>5 (4 chunks of 8192: hi [0,4096), lo [4096,8192))
//   within: (o>>4)*512 + lane*8 + (k&7), lane = (o&15) + 16*((k>>3)&3)
// ---------------------------------------------------------------------------
__global__ __launch_bounds__(256) void pack6(const float* __restrict__ KNopen,
                                             const float* __restrict__ KEopen,
                                             const float* __restrict__ KN,
                                             unsigned short* __restrict__ dst) {
  const int idx = blockIdx.x * 256 + threadIdx.x;  // 16384 per matrix
  const int m = blockIdx.y;                        // 6 matrices
  const int o = idx >> 7, k = idx & 127;
  const float* src;
  if (m == 0) src = KNopen;
  else if (m == 1) src = KEopen;
  else src = KN + (m - 2) * 16384;
  const float val = src[o * 128 + k];
  const unsigned short hi = f2bf(val);
  const unsigned short lo = f2bf(val - bf2f(hi));
  const int lane = (o & 15) + 16 * ((k >> 3) & 3);
  const int base =
      m * 32768 + (k >> 5) * 8192 + (o >> 4) * 512 + lane * 8 + (k & 7);
  dst[base] = hi;
  dst[base + 4096] = lo;
}

// prep_close_w: pack M1 = KNclose@KEopen (p=0) and Kc = KNclose (p=1).
__global__ __launch_bounds__(256) void prep_close_w(
    const float* __restrict__ KNclose, const float* __restrict__ KEopen,
    unsigned short* __restrict__ Apack) {
  const int idx = blockIdx.x * 256 + threadIdx.x;  // 32768
  const int p = idx >> 14, ok = idx & 16383;
  const int o = ok >> 7, k = ok & 127;
  float val;
  if (p == 0) {
    float s = 0.f;
    for (int m = 0; m < 128; ++m)
      s = fmaf(KNclose[o * 128 + m], KEopen[m * 128 + k], s);
    val = s;
  } else {
    val = KNclose[o * 128 + k];
  }
  const unsigned short hi = f2bf(val);
  const unsigned short lo = f2bf(val - bf2f(hi));
  const int chunk = p * 4 + (k >> 5);
  const int lane = (o & 15) + 16 * ((k >> 3) & 3);
  const int base = chunk * 8192 + (o >> 4) * 512 + lane * 8 + (k & 7);
  Apack[base] = hi;
  Apack[base + 4096] = lo;
}

// ---------------------------------------------------------------------------
// gemm_e_mfma: X [128,N] channel-major; Y[e][o] = sum_k K[o][k]X[k][e],
// stored [N,128].
// ---------------------------------------------------------------------------
__global__ __launch_bounds__(256, 2) void gemm_e_mfma(
    const float* __restrict__ X, const unsigned short* __restrict__ Wp,
    const int N, float* __restrict__ Yt) {
  __shared__ float4 Asf[1024];
  const int tid = threadIdx.x;
  const int l = tid & 63, w = tid >> 6;
  const int er = l & 15, kg = l >> 4;
  const long e0 = (long)blockIdx.x * 128;

  f32x4 acc[8][2];
#pragma unroll
  for (int of = 0; of < 8; ++of)
#pragma unroll
    for (int f = 0; f < 2; ++f) acc[of][f] = (f32x4){0.f, 0.f, 0.f, 0.f};

  long e_f[2];
  bool ev[2];
#pragma unroll
  for (int f = 0; f < 2; ++f) {
    long e = e0 + 32 * w + 16 * f + er;
    ev[f] = (e < N);
    e_f[f] = ev[f] ? e : (long)(N - 1);
  }

  const short8v* Ap = (const short8v*)Asf;

  for (int ks = 0; ks < 4; ++ks) {
    const float4* src = (const float4*)Wp + ks * 1024;
    __syncthreads();
    Asf[tid] = src[tid];
    Asf[tid + 256] = src[tid + 256];
    Asf[tid + 512] = src[tid + 512];
    Asf[tid + 768] = src[tid + 768];
    __syncthreads();

    short8v bh[2], bl[2];
#pragma unroll
    for (int f = 0; f < 2; ++f) {
      const float* col = X + e_f[f];
      const int kbase = 32 * ks + 8 * kg;
      float xv[8];
#pragma unroll
      for (int j = 0; j < 8; ++j) xv[j] = col[(long)(kbase + j) * N];
#pragma unroll
      for (int j = 0; j < 8; ++j) {
        const unsigned short h = f2bf(xv[j]);
        const unsigned short lo = f2bf(xv[j] - bf2f(h));
        bh[f][j] = (short)h;
        bl[f][j] = (short)lo;
      }
    }

#pragma unroll
    for (int of = 0; of < 8; ++of) {
      const short8v ah = Ap[of * 64 + l];
      const short8v al = Ap[512 + of * 64 + l];
#pragma unroll
      for (int f = 0; f < 2; ++f) {
        acc[of][f] =
            __builtin_amdgcn_mfma_f32_16x16x32_bf16(ah, bh[f], acc[of][f], 0, 0, 0);
        acc[of][f] =
            __builtin_amdgcn_mfma_f32_16x16x32_bf16(ah, bl[f], acc[of][f], 0, 0, 0);
        acc[of][f] =
            __builtin_amdgcn_mfma_f32_16x16x32_bf16(al, bh[f], acc[of][f], 0, 0, 0);
      }
    }
  }

#pragma unroll
  for (int of = 0; of < 8; ++of) {
#pragma unroll
    for (int f = 0; f < 2; ++f) {
      if (!ev[f]) continue;
      *(f32x4*)&Yt[e_f[f] * 128 + of * 16 + 4 * kg] = acc[of][f];
    }
  }
}

// ---------------------------------------------------------------------------
// gemm_n_mfma: X [N,128] row-major; Y[n][o] = sum_k X[n][k]K[o][k].
// MODE 0: store [N,128]. MODE 2: store [128,N].
// ---------------------------------------------------------------------------
template <int MODE>
__global__ __launch_bounds__(256, 2) void gemm_n_mfma(
    const float* __restrict__ X, const unsigned short* __restrict__ Wp,
    const int N, float* __restrict__ Y) {
  __shared__ float4 Asf[1024];
  const int tid = threadIdx.x;
  const int l = tid & 63, w = tid >> 6;
  const int er = l & 15, kg = l >> 4;
  const long n0 = (long)blockIdx.x * 128;

  f32x4 acc[8][2];
#pragma unroll
  for (int of = 0; of < 8; ++of)
#pragma unroll
    for (int f = 0; f < 2; ++f) acc[of][f] = (f32x4){0.f, 0.f, 0.f, 0.f};

  long n_f[2];
  bool nv[2];
#pragma unroll
  for (int f = 0; f < 2; ++f) {
    long n = n0 + 32 * w + 16 * f + er;
    nv[f] = (n < N);
    n_f[f] = nv[f] ? n : (long)(N - 1);
  }

  const short8v* Ap = (const short8v*)Asf;

  for (int ks = 0; ks < 4; ++ks) {
    const float4* src = (const float4*)Wp + ks * 1024;
    __syncthreads();
    Asf[tid] = src[tid];
    Asf[tid + 256] = src[tid + 256];
    Asf[tid + 512] = src[tid + 512];
    Asf[tid + 768] = src[tid + 768];
    __syncthreads();

    short8v bh[2], bl[2];
#pragma unroll
    for (int f = 0; f < 2; ++f) {
      const float* row = X + n_f[f] * 128 + 32 * ks + 8 * kg;
      const float4 v0 = *(const float4*)row;
      const float4 v1 = *(const float4*)(row + 4);
      float xv[8] = {v0.x, v0.y, v0.z, v0.w, v1.x, v1.y, v1.z, v1.w};
#pragma unroll
      for (int j = 0; j < 8; ++j) {
        const unsigned short h = f2bf(xv[j]);
        const unsigned short lo = f2bf(xv[j] - bf2f(h));
        bh[f][j] = (short)h;
        bl[f][j] = (short)lo;
      }
    }

#pragma unroll
    for (int of = 0; of < 8; ++of) {
      const short8v ah = Ap[of * 64 + l];
      const short8v al = Ap[512 + of * 64 + l];
#pragma unroll
      for (int f = 0; f < 2; ++f) {
        acc[of][f] =
            __builtin_amdgcn_mfma_f32_16x16x32_bf16(ah, bh[f], acc[of][f], 0, 0, 0);
        acc[of][f] =
            __builtin_amdgcn_mfma_f32_16x16x32_bf16(ah, bl[f], acc[of][f], 0, 0, 0);
        acc[of][f] =
            __builtin_amdgcn_mfma_f32_16x16x32_bf16(al, bh[f], acc[of][f], 0, 0, 0);
      }
    }
  }

  if (MODE == 0) {
#pragma unroll
    for (int of = 0; of < 8; ++of) {
#pragma unroll
      for (int f = 0; f < 2; ++f) {
        if (!nv[f]) continue;
        *(f32x4*)&Y[n_f[f] * 128 + of * 16 + 4 * kg] = acc[of][f];
      }
    }
  } else {  // MODE 2: transposed store [128,N]
#pragma unroll
    for (int of = 0; of < 8; ++of) {
#pragma unroll
      for (int f = 0; f < 2; ++f) {
        if (!nv[f]) continue;
#pragma unroll
        for (int r = 0; r < 4; ++r) {
          const long o = of * 16 + 4 * kg + r;
          Y[o * N + n_f[f]] = acc[of][f][r];
        }
      }
    }
  }
}

// ---------------------------------------------------------------------------
// gemm_n1 (fp32): X [N,128]; relu + store [N,128] + per-channel stats.
// ---------------------------------------------------------------------------
__global__ __launch_bounds__(256, 2) void gemm_n1(
    const float* __restrict__ X, const float* __restrict__ Kmat, const int N,
    float* __restrict__ Y, float* __restrict__ statS,
    float* __restrict__ statQ) {
  __shared__ float Xs[64 * 33];
  __shared__ float Ks[32 * 132];
  __shared__ float red[2 * 128 * 17];
  const int tid = threadIdx.x;
  const int ng = tid & 15, og = tid >> 4;
  const long n0 = (long)blockIdx.x * 64;

  float acc[4][8];
#pragma unroll
  for (int q = 0; q < 4; ++q)
#pragma unroll
    for (int j = 0; j < 8; ++j) acc[q][j] = 0.f;

  for (int kc = 0; kc < 128; kc += 32) {
#pragma unroll
    for (int i = 0; i < 2; ++i) {
      int f4i = tid + 256 * i;
      int n = f4i >> 3, c4 = (f4i & 7) << 2;
      long gn = n0 + n;
      float4 v = f4z();
      if (gn < N) v = *(const float4*)&X[gn * 128 + kc + c4];
      Xs[n * 33 + c4 + 0] = v.x;
      Xs[n * 33 + c4 + 1] = v.y;
      Xs[n * 33 + c4 + 2] = v.z;
      Xs[n * 33 + c4 + 3] = v.w;
    }
#pragma unroll
    for (int i = 0; i < 4; ++i) {
      int f4i = tid + 256 * i;
      int o = f4i >> 3, c4 = (f4i & 7) << 2;
      float4 v = *(const float4*)&Kmat[o * 128 + kc + c4];
      Ks[(c4 + 0) * 132 + o] = v.x;
      Ks[(c4 + 1) * 132 + o] = v.y;
      Ks[(c4 + 2) * 132 + o] = v.z;
      Ks[(c4 + 3) * 132 + o] = v.w;
    }
    __syncthreads();
#pragma unroll
    for (int kk = 0; kk < 32; ++kk) {
      float xv[4];
#pragma unroll
      for (int q = 0; q < 4; ++q) xv[q] = Xs[(4 * ng + q) * 33 + kk];
      const float4 k0 = *(const float4*)&Ks[kk * 132 + 8 * og];
      const float4 k1 = *(const float4*)&Ks[kk * 132 + 8 * og + 4];
      float kv[8] = {k0.x, k0.y, k0.z, k0.w, k1.x, k1.y, k1.z, k1.w};
#pragma unroll
      for (int q = 0; q < 4; ++q)
#pragma unroll
        for (int j = 0; j < 8; ++j) acc[q][j] = fmaf(xv[q], kv[j], acc[q][j]);
    }
    __syncthreads();
  }

#pragma unroll
  for (int q = 0; q < 4; ++q)
#pragma unroll
    for (int j = 0; j < 8; ++j) acc[q][j] = fmaxf(acc[q][j], 0.f);
#pragma unroll
  for (int q = 0; q < 4; ++q) {
    long n = n0 + 4 * ng + q;
    if (n < N) {
      *(float4*)&Y[n * 128 + 8 * og] =
          make_float4(acc[q][0], acc[q][1], acc[q][2], acc[q][3]);
      *(float4*)&Y[n * 128 + 8 * og + 4] =
          make_float4(acc[q][4], acc[q][5], acc[q][6], acc[q][7]);
    }
  }
  float* redS = red;
  float* redQ = red + 128 * 17;
#pragma unroll
  for (int j = 0; j < 8; ++j) {
    int o = 8 * og + j;
    float s = acc[0][j] + acc[1][j] + acc[2][j] + acc[3][j];
    float qq = acc[0][j] * acc[0][j] + acc[1][j] * acc[1][j] +
               acc[2][j] * acc[2][j] + acc[3][j] * acc[3][j];
    redS[o * 17 + ng] = s;
    redQ[o * 17 + ng] = qq;
  }
  __syncthreads();
  if (tid < 128) {
    float s = 0.f, qq = 0.f;
#pragma unroll
    for (int g = 0; g < 16; ++g) {
      s += redS[tid * 17 + g];
      qq += redQ[tid * 17 + g];
    }
    atomicAdd(&statS[tid], s);
    atomicAdd(&statQ[tid], qq);
  }
}

// ---------------------------------------------------------------------------
// close_edge_mfma: out[o][e] = sum_k M1[o][k]*xe[k][e] + Kc[o][k]*Sacc[e][k]
// ---------------------------------------------------------------------------
__global__ __launch_bounds__(256, 2) void close_edge_mfma(
    const float* __restrict__ xe, const float* __restrict__ Sacc,
    const unsigned short* __restrict__ Apack, const int nE,
    float* __restrict__ out) {
  __shared__ float4 Asf[1024];
  const int tid = threadIdx.x;
  const int l = tid & 63, w = tid >> 6;
  const int er = l & 15;
  const int kg = l >> 4;
  const long e0 = (long)blockIdx.x * 128;

  f32x4 acc[8][2];
#pragma unroll
  for (int of = 0; of < 8; ++of)
#pragma unroll
    for (int f = 0; f < 2; ++f) acc[of][f] = (f32x4){0.f, 0.f, 0.f, 0.f};

  long e_f[2];
  bool ev[2];
#pragma unroll
  for (int f = 0; f < 2; ++f) {
    long e = e0 + 32 * w + 16 * f + er;
    ev[f] = (e < nE);
    e_f[f] = ev[f] ? e : (long)(nE - 1);
  }

  const short8v* Ap = (const short8v*)Asf;

  for (int p = 0; p < 2; ++p) {
    for (int ks = 0; ks < 4; ++ks) {
      const float4* src = (const float4*)Apack + (p * 4 + ks) * 1024;
      __syncthreads();
      Asf[tid] = src[tid];
      Asf[tid + 256] = src[tid + 256];
      Asf[tid + 512] = src[tid + 512];
      Asf[tid + 768] = src[tid + 768];
      __syncthreads();

      short8v bh[2], bl[2];
#pragma unroll
      for (int f = 0; f < 2; ++f) {
        float xv[8];
        if (p == 0) {
          const float* col = xe + e_f[f];
          const int kbase = 32 * ks + 8 * kg;
#pragma unroll
          for (int j = 0; j < 8; ++j) xv[j] = col[(long)(kbase + j) * nE];
        } else {
          const float* row = Sacc + e_f[f] * 128 + 32 * ks + 8 * kg;
          const float4 v0 = *(const float4*)row;
          const float4 v1 = *(const float4*)(row + 4);
          xv[0] = v0.x; xv[1] = v0.y; xv[2] = v0.z; xv[3] = v0.w;
          xv[4] = v1.x; xv[5] = v1.y; xv[6] = v1.z; xv[7] = v1.w;
        }
#pragma unroll
        for (int j = 0; j < 8; ++j) {
          const unsigned short h = f2bf(xv[j]);
          const unsigned short lo = f2bf(xv[j] - bf2f(h));
          bh[f][j] = (short)h;
          bl[f][j] = (short)lo;
        }
      }

#pragma unroll
      for (int of = 0; of < 8; ++of) {
        const short8v ah = Ap[of * 64 + l];
        const short8v al = Ap[512 + of * 64 + l];
#pragma unroll
        for (int f = 0; f < 2; ++f) {
          acc[of][f] =
              __builtin_amdgcn_mfma_f32_16x16x32_bf16(ah, bh[f], acc[of][f], 0, 0, 0);
          acc[of][f] =
              __builtin_amdgcn_mfma_f32_16x16x32_bf16(ah, bl[f], acc[of][f], 0, 0, 0);
          acc[of][f] =
              __builtin_amdgcn_mfma_f32_16x16x32_bf16(al, bh[f], acc[of][f], 0, 0, 0);
        }
      }
    }
  }

#pragma unroll
  for (int of = 0; of < 8; ++of) {
#pragma unroll
    for (int f = 0; f < 2; ++f) {
      if (!ev[f]) continue;
      const long e = e_f[f];
#pragma unroll
      for (int r = 0; r < 4; ++r) {
        const long o = of * 16 + 4 * kg + r;
        out[o * nE + e] = acc[of][f][r];
      }
    }
  }
}

// ---------------------------------------------------------------------------
// CSR build. Entry = (e<<1)|sign (sign 1 => n was j). adjO = other endpoint.
// ---------------------------------------------------------------------------
__global__ __launch_bounds__(256) void count_deg(const int* __restrict__ iInd,
                                                 const int* __restrict__ jInd,
                                                 const int nE,
                                                 int* __restrict__ cnt) {
  const int e = blockIdx.x * 256 + threadIdx.x;
  if (e >= nE) return;
  atomicAdd(&cnt[iInd[e]], 1);
  atomicAdd(&cnt[jInd[e]], 1);
}

__global__ __launch_bounds__(1024) void scan_rowptr(const int* __restrict__ cnt,
                                                    int* __restrict__ rp,
                                                    const int nN) {
  __shared__ int buf[1024];
  __shared__ int carry;
  const int tid = threadIdx.x;
  if (tid == 0) {
    carry = 0;
    rp[0] = 0;
  }
  __syncthreads();
  for (int base = 0; base < nN; base += 1024) {
    int idx = base + tid;
    int v = (idx < nN) ? cnt[idx] : 0;
    buf[tid] = v;
    __syncthreads();
    for (int off = 1; off < 1024; off <<= 1) {
      int t = (tid >= off) ? buf[tid - off] : 0;
      __syncthreads();
      buf[tid] += t;
      __syncthreads();
    }
    if (idx < nN) rp[idx + 1] = buf[tid] + carry;
    __syncthreads();
    if (tid == 0) carry += buf[1023];
    __syncthreads();
  }
}

__global__ __launch_bounds__(256) void fill_adj(const int* __restrict__ iInd,
                                                const int* __restrict__ jInd,
                                                const int nE,
                                                const int* __restrict__ rp,
                                                int* __restrict__ cur,
                                                int* __restrict__ adj,
                                                int* __restrict__ adjO) {
  const int e = blockIdx.x * 256 + threadIdx.x;
  if (e >= nE) return;
  const int ii = iInd[e], jj = jInd[e];
  int s1 = atomicAdd(&cur[ii], 1);
  adj[rp[ii] + s1] = (e << 1);
  adjO[rp[ii] + s1] = jj;
  int s2 = atomicAdd(&cur[jj], 1);
  adj[rp[jj] + s2] = (e << 1) | 1;
  adjO[rp[jj] + s2] = ii;
}

// ---------------------------------------------------------------------------
// div_open: Dacc[n,:] = sum_{(e,s) in adj(n)} +-E[e,:]   (E = Eopen [nE,128])
// ---------------------------------------------------------------------------
__global__ __launch_bounds__(256) void div_open(
    const float* __restrict__ E, const int* __restrict__ rp,
    const int* __restrict__ adj, float* __restrict__ Dacc, const int nN) {
  const int cg = threadIdx.x & 31, slot = threadIdx.x >> 5;
  const long n = (long)blockIdx.x * 8 + slot;
  if (n >= nN) return;
  const float4* E4 = (const float4*)E;
  float4 acc = f4z();
  const int b = rp[n], en = rp[n + 1];
  for (int k = b; k < en; ++k) {
    const int ent = adj[k];
    const long e = ent >> 1;
    const float4 v = E4[e * 32 + cg];
    if (ent & 1) {
      acc.x -= v.x; acc.y -= v.y; acc.z -= v.z; acc.w -= v.w;
    } else {
      acc.x += v.x; acc.y += v.y; acc.z += v.z; acc.w += v.w;
    }
  }
  ((float4*)Dacc)[n * 32 + cg] = acc;
}

// ---------------------------------------------------------------------------
// div_fused: Dacc[n,:] += sum_{(e,s) in adj(n)} +- r_e, with
// r_e = H*relu((W[i_e]-W[j_e]-mu)*sig) computed on the fly from LLC-resident
// W (25MB). y = s*(W[n]-W[other]); contribution = s*r.
// ---------------------------------------------------------------------------
__global__ __launch_bounds__(256) void div_fused(
    const float* __restrict__ W, const int* __restrict__ rp,
    const int* __restrict__ adj, const int* __restrict__ adjO,
    const float* __restrict__ mean, const float* __restrict__ rsig,
    float* __restrict__ Dacc, const int nN) {
  const int cg = threadIdx.x & 31, slot = threadIdx.x >> 5;
  const long n = (long)blockIdx.x * 8 + slot;
  if (n >= nN) return;
  const float4* W4 = (const float4*)W;
  const float4 mu = *(const float4*)&mean[cg * 4];
  const float4 sg = *(const float4*)&rsig[cg * 4];
  const float4 wn = W4[n * 32 + cg];
  float4 acc = ((const float4*)Dacc)[n * 32 + cg];
  const int b = rp[n], en = rp[n + 1];
  for (int k = b; k < en; ++k) {
    const float s = (adj[k] & 1) ? -1.f : 1.f;
    const long o = adjO[k];
    const float4 wo = W4[o * 32 + cg];
    const float t0 = fmaxf((s * (wn.x - wo.x) - mu.x) * sg.x, 0.f);
    const float t1 = fmaxf((s * (wn.y - wo.y) - mu.y) * sg.y, 0.f);
    const float t2 = fmaxf((s * (wn.z - wo.z) - mu.z) * sg.z, 0.f);
    const float t3 = fmaxf((s * (wn.w - wo.w) - mu.w) * sg.w, 0.f);
    const float sh = s * HSTEP;
    acc.x = fmaf(sh, t0, acc.x);
    acc.y = fmaf(sh, t1, acc.y);
    acc.z = fmaf(sh, t2, acc.z);
    acc.w = fmaf(sh, t3, acc.w);
  }
  ((float4*)Dacc)[n * 32 + cg] = acc;
}

// ---------------------------------------------------------------------------
// compute_sacc: Sacc[e,:] = sum_l H*relu((W_l[i]-W_l[j]-mu_l)*sig_l).
// One coalesced write; W_l gathers hit LLC (4x25MB).
// ---------------------------------------------------------------------------
__global__ __launch_bounds__(256) void compute_sacc(
    const float* __restrict__ Wb, const long lstr4,
    const int* __restrict__ iInd, const int* __restrict__ jInd, const int nE,
    const float* __restrict__ meanAll, const float* __restrict__ rsigAll,
    float* __restrict__ Sacc) {
  const int tid = threadIdx.x;
  const int cg = tid & 31, slot = tid >> 5;
  float4 mu[4], sg[4];
#pragma unroll
  for (int l = 0; l < 4; ++l) {
    mu[l] = *(const float4*)&meanAll[l * 128 + cg * 4];
    sg[l] = *(const float4*)&rsigAll[l * 128 + cg * 4];
  }
  const float4* W4 = (const float4*)Wb;
  float4* S4 = (float4*)Sacc;
  long start = (long)blockIdx.x * 512;
  long end = start + 512;
  if (end > nE) end = nE;
  for (long e = start + slot; e < end; e += 8) {
    const long ii = iInd[e], jj = jInd[e];
    float4 acc = f4z();
#pragma unroll
    for (int l = 0; l < 4; ++l) {
      const float4 wi = W4[l * lstr4 + ii * 32 + cg];
      const float4 wj = W4[l * lstr4 + jj * 32 + cg];
      acc.x += HSTEP * fmaxf(((wi.x - wj.x) - mu[l].x) * sg[l].x, 0.f);
      acc.y += HSTEP * fmaxf(((wi.y - wj.y) - mu[l].y) * sg[l].y, 0.f);
      acc.z += HSTEP * fmaxf(((wi.z - wj.z) - mu[l].z) * sg[l].z, 0.f);
      acc.w += HSTEP * fmaxf(((wi.w - wj.w) - mu[l].w) * sg[l].w, 0.f);
    }
    S4[e * 32 + cg] = acc;
  }
}

// ---------------------------------------------------------------------------
// Edge pass 1: per-channel sum/sumsq of y = W[i]-W[j].
// ---------------------------------------------------------------------------
__global__ __launch_bounds__(256) void edge_pass1(
    const float* __restrict__ W, const int* __restrict__ iInd,
    const int* __restrict__ jInd, const int nE, float* __restrict__ statS,
    float* __restrict__ statQ) {
  __shared__ float4 rs[256];
  __shared__ float4 rq[256];
  const int tid = threadIdx.x;
  const int cg = tid & 31, slot = tid >> 5;
  const float4* W4 = (const float4*)W;
  float4 s = f4z(), q = f4z();
  long start = (long)blockIdx.x * 512;
  long end = start + 512;
  if (end > nE) end = nE;
  for (long e = start + slot; e < end; e += 8) {
    const int ii = iInd[e], jj = jInd[e];
    const float4 wi = W4[(long)ii * 32 + cg];
    const float4 wj = W4[(long)jj * 32 + cg];
    const float y0 = wi.x - wj.x, y1 = wi.y - wj.y;
    const float y2 = wi.z - wj.z, y3 = wi.w - wj.w;
    s.x += y0; s.y += y1; s.z += y2; s.w += y3;
    q.x = fmaf(y0, y0, q.x); q.y = fmaf(y1, y1, q.y);
    q.z = fmaf(y2, y2, q.z); q.w = fmaf(y3, y3, q.w);
  }
  rs[tid] = s;
  rq[tid] = q;
  __syncthreads();
  if (tid < 32) {
    float4 S = rs[tid], Q = rq[tid];
#pragma unroll
    for (int g = 1; g < 8; ++g) {
      float4 a = rs[tid + 32 * g], b = rq[tid + 32 * g];
      S.x += a.x; S.y += a.y; S.z += a.z; S.w += a.w;
      Q.x += b.x; Q.y += b.y; Q.z += b.z; Q.w += b.w;
    }
    atomicAdd(&statS[tid * 4 + 0], S.x);
    atomicAdd(&statS[tid * 4 + 1], S.y);
    atomicAdd(&statS[tid * 4 + 2], S.z);
    atomicAdd(&statS[tid * 4 + 3], S.w);
    atomicAdd(&statQ[tid * 4 + 0], Q.x);
    atomicAdd(&statQ[tid * 4 + 1], Q.y);
    atomicAdd(&statQ[tid * 4 + 2], Q.z);
    atomicAdd(&statQ[tid * 4 + 3], Q.w);
  }
}

// ---------------------------------------------------------------------------
__global__ void fin_stats(const float* __restrict__ S,
                          const float* __restrict__ Q, const float cnt,
                          float* __restrict__ mean, float* __restrict__ rsig) {
  const int c = threadIdx.x;  // 128
  const float mu = S[c] / cnt;
  const float var = Q[c] - cnt * mu * mu;
  mean[c] = mu;
  rsig[c] = rsqrtf(var + TVEPS);
}

__global__ __launch_bounds__(256) void apply_node(
    const float* __restrict__ R, const float* __restrict__ mean,
    const float* __restrict__ rsig, float* __restrict__ xnt,
    const long total4) {
  const long idx = (long)blockIdx.x * 256 + threadIdx.x;
  if (idx >= total4) return;
  const int o4 = (int)(idx & 31) * 4;
  const float4 m = *(const float4*)&mean[o4];
  const float4 s = *(const float4*)&rsig[o4];
  const float4 r = ((const float4*)R)[idx];
  float4 x = ((float4*)xnt)[idx];
  x.x += HSTEP * fmaxf((r.x - m.x) * s.x, 0.f);
  x.y += HSTEP * fmaxf((r.y - m.y) * s.y, 0.f);
  x.z += HSTEP * fmaxf((r.z - m.z) * s.z, 0.f);
  x.w += HSTEP * fmaxf((r.w - m.w) * s.w, 0.f);
  ((float4*)xnt)[idx] = x;
}

// ---------------------------------------------------------------------------
extern "C" void kernel_launch(void* const* d_in, const int* in_sizes, int n_in,
                              void* d_out, int out_size, void* d_ws,
                              size_t ws_size, hipStream_t stream) {
  const float* xn = (const float*)d_in[0];
  const float* xe = (const float*)d_in[1];
  const int* iInd = (const int*)d_in[2];
  const int* jInd = (const int*)d_in[3];
  const float* KNopen = (const float*)d_in[4];
  const float* KEopen = (const float*)d_in[5];
  const float* KNclose = (const float*)d_in[6];
  const float* KN = (const float*)d_in[8];
  const float* KE = (const float*)d_in[9];

  const int nN = in_sizes[0] / 128;
  const int nE = in_sizes[2];

  float* out_xn = (float*)d_out;
  float* out_xe = (float*)d_out + (size_t)128 * nN;

  // ---- workspace (~318MB, below round-4's known-good ~363MB) ----
  float* ws = (float*)d_ws;
  size_t off = 0;
  float* Sacc = ws + off; off += (size_t)nE * 128;  // 256MB; aliases Eopen
  float* Dacc = ws + off; off += (size_t)nN * 128;  // running divergence
  float* xnt  = ws + off; off += (size_t)nN * 128;
  unsigned short* Apack = (unsigned short*)(ws + off); off += 32768;
  unsigned short* Wpack = (unsigned short*)(ws + off); off += 98304;
  float* stats = ws + off; off += 2048;
  float* statS = stats;        float* statQ = stats + 128;
  float* statS2 = stats + 256; float* statQ2 = stats + 384;
  float* meanN = stats + 512;  float* rsigN = stats + 640;
  float* meanEall = stats + 768;
  float* rsigEall = stats + 1280;
  int* rp   = (int*)(ws + off); off += (size_t)nN + 1 + 63;
  int* cnt  = (int*)(ws + off); off += nN;
  int* cur  = (int*)(ws + off); off += nN;
  int* adj  = (int*)(ws + off); off += (size_t)2 * nE;
  int* adjO = (int*)(ws + off); off += (size_t)2 * nE;
  float* Eopen = Sacc;  // alias: Eopen dead after div_open; Sacc written last

  // ---- d_out scratch: out_xe region (256MB) is dead until the last two
  // dispatches. compute_sacc (last reader of Wb) precedes close_edge_mfma
  // (first writer of out_xe) on the same stream. R only read by apply_node.
  float* Wb = out_xe;                          // 4 x nN*128 = 102.4MB
  float* R  = out_xe + (size_t)4 * nN * 128;   // 25.6MB

  const int gN = (nN + 63) / 64;
  const int gNm = (nN + 127) / 128;
  const int gEm = (nE + 127) / 128;
  const int gP = (nE + 511) / 512;
  const int gEdge = (nE + 255) / 256;
  const int gGath = (nN + 7) / 8;
  const int gA = (int)(((long)nN * 32 + 255) / 256);
  const long lstr4 = (long)nN * 32;  // layer stride in float4

  // ---- CSR build ----
  hipMemsetAsync(cnt, 0, (size_t)nN * sizeof(int), stream);
  hipMemsetAsync(cur, 0, (size_t)nN * sizeof(int), stream);
  count_deg<<<gEdge, 256, 0, stream>>>(iInd, jInd, nE, cnt);
  scan_rowptr<<<1, 1024, 0, stream>>>(cnt, rp, nN);
  fill_adj<<<gEdge, 256, 0, stream>>>(iInd, jInd, nE, rp, cur, adj, adjO);

  // ---- weight packs ----
  pack6<<<dim3(64, 6), 256, 0, stream>>>(KNopen, KEopen, KN, Wpack);
  prep_close_w<<<128, 256, 0, stream>>>(KNclose, KEopen, Apack);

  // ---- open ----
  gemm_e_mfma<<<gNm, 256, 0, stream>>>(xn, Wpack, nN, xnt);
  gemm_e_mfma<<<gEm, 256, 0, stream>>>(xe, Wpack + 32768, nE, Eopen);
  div_open<<<gGath, 256, 0, stream>>>(Eopen, rp, adj, Dacc, nN);

  // ---- layers ----
  for (int layer = 0; layer < 4; ++layer) {
    float* Wl = Wb + (size_t)layer * nN * 128;
    float* meanE = meanEall + 128 * layer;
    float* rsigE = rsigEall + 128 * layer;
    hipMemsetAsync(stats, 0, 512 * sizeof(float), stream);
    gemm_n_mfma<0><<<gNm, 256, 0, stream>>>(
        xnt, Wpack + (size_t)(2 + layer) * 32768, nN, Wl);
    edge_pass1<<<gP, 256, 0, stream>>>(Wl, iInd, jInd, nE, statS, statQ);
    fin_stats<<<1, 128, 0, stream>>>(statS, statQ, (float)nE, meanE, rsigE);
    div_fused<<<gGath, 256, 0, stream>>>(Wl, rp, adj, adjO, meanE, rsigE,
                                         Dacc, nN);
    gemm_n1<<<gN, 256, 0, stream>>>(Dacc, KE + layer * 16384, nN, R, statS2,
                                    statQ2);
    fin_stats<<<1, 128, 0, stream>>>(statS2, statQ2, (float)nN, meanN, rsigN);
    apply_node<<<gA, 256, 0, stream>>>(R, meanN, rsigN, xnt, (long)nN * 32);
  }

  // ---- Sacc (once) + close ----
  compute_sacc<<<gP, 256, 0, stream>>>(Wb, lstr4, iInd, jInd, nE, meanEall,
                                       rsigEall, Sacc);
  gemm_n_mfma<2><<<gNm, 256, 0, stream>>>(xnt, Apack + 32768, nN, out_xn);
  close_edge_mfma<<<gEm, 256, 0, stream>>>(xe, Sacc, Apack, nE, out_xe);
}